// Round 1
// baseline (3813.530 us; speedup 1.0000x reference)
//
#include <hip/hip_runtime.h>
#include <hip/hip_bf16.h>

#define TT 512
#define BB 64
#define II 128
#define HH 512
#define OO 128
#define KLAG 32
#define GWG 32      // h-slice workgroups (16 channels each)
#define HC 16
#define KKX 4       // K-blocks (of 32) coming from x
#define KKT 20      // total K-blocks (640/32)

typedef __attribute__((ext_vector_type(8))) short short8;
typedef __attribute__((ext_vector_type(4))) float f32x4;
typedef unsigned short u16;

__device__ __forceinline__ float sigmoidf_(float x){ return 1.f/(1.f+__expf(-x)); }
__device__ __forceinline__ float tanhf_(float x){ float e = __expf(2.f*x); return 1.f - 2.f/(e+1.f); }
__device__ __forceinline__ u16 f2bf(float f){
  __hip_bfloat16 h = __float2bfloat16(f);
  u16 u; __builtin_memcpy(&u, &h, 2); return u;
}

// ---- prep: cast inputs x to bf16 ([T][B][128]) ----
__global__ void k_cast_x(const float* __restrict__ x, u16* __restrict__ xb, int n4){
  int i = blockIdx.x*256 + threadIdx.x;
  if (i >= n4) return;
  float4 v = ((const float4*)x)[i];
  ushort4 o;
  o.x = f2bf(v.x); o.y = f2bf(v.y); o.z = f2bf(v.z); o.w = f2bf(v.w);
  ((ushort4*)xb)[i] = o;
}

// ---- prep: pack W_i/W_o/W_c into MFMA B-fragment layout ----
// flat idx = (((gh*3+gate)*KKT + kk)*64 + lane)*8 + j
__global__ void k_pack_w(const float* __restrict__ Wi, const float* __restrict__ Wo,
                         const float* __restrict__ Wc, u16* __restrict__ wp){
  int idx = blockIdx.x*256 + threadIdx.x;          // 983040 total
  int j    = idx & 7;
  int lane = (idx >> 3) & 63;
  int kk   = (idx >> 9) % KKT;
  int rest = (idx >> 9) / KKT;
  int gate = rest % 3;
  int gh   = rest / 3;
  int k    = kk*32 + ((lane>>4)<<3) + j;           // row of W (0..639)
  int col  = gh*HC + (lane & 15);                  // col of W (0..511)
  const float* W = (gate==0) ? Wi : ((gate==1) ? Wo : Wc);
  wp[idx] = f2bf(W[(size_t)k*HH + col]);
}

// ---- prep: pack W_out, flat idx = ((nt*16+kk)*64+lane)*8+j ----
__global__ void k_pack_wo(const float* __restrict__ Wout, u16* __restrict__ wp){
  int idx = blockIdx.x*256 + threadIdx.x;          // 65536 total
  int j    = idx & 7;
  int lane = (idx >> 3) & 63;
  int kk   = (idx >> 9) & 15;
  int nt   = idx >> 13;
  int k    = kk*32 + ((lane>>4)<<3) + j;           // 0..511
  int col  = nt*16 + (lane & 15);                  // 0..127
  wp[idx] = f2bf(Wout[(size_t)k*OO + col]);
}

// ---- prep: zero h exchange buffers + flags ----
__global__ void k_zero(unsigned int* __restrict__ hex_u32, int n, int* __restrict__ flags){
  int i = blockIdx.x*256 + threadIdx.x;
  if (i < n) hex_u32[i] = 0;
  if (blockIdx.x == 0){
    for (int f = threadIdx.x; f < GWG*16; f += 256) flags[f] = 0;
  }
}

// ---- the persistent recurrence kernel: 32 WGs x 256 threads ----
__global__ __launch_bounds__(256, 1) void k_recur(
    const u16* __restrict__ xb,        // [T][B][128] bf16
    const u16* __restrict__ wp,        // packed gate weights
    const float* __restrict__ bi_p, const float* __restrict__ bo_p,
    const float* __restrict__ bc_p, const float* __restrict__ dv,
    u16* __restrict__ hex,             // [2][B][H] bf16 exchange
    u16* __restrict__ hseq,            // [T][B][H] bf16
    float* __restrict__ hlast,         // [B][H] f32
    float* __restrict__ hclast,        // [K][B][H] f32
    int* __restrict__ flags)           // [32*16] padded
{
  const int gh  = blockIdx.x;
  const int tid = threadIdx.x;
  const int w = tid >> 6, l = tid & 63, lg = l >> 4, lr = l & 15;
  const int ch = gh*HC + lr;                     // global channel for this thread's outputs

  // fractional-differencing weights v_1..v_32 for this channel
  float d = 0.5f * sigmoidf_(dv[ch]);
  float v[KLAG];
  float vc = 1.f;
  #pragma unroll
  for (int j = 0; j < KLAG; ++j){ vc *= ((float)j - d)/((float)(j+1)); v[j] = vc; }
  const float bi = bi_p[ch], bo = bo_p[ch], bc = bc_p[ch];

  // c history in registers: hist[r][q] = c_{t-1-q} for batch row (browb+r)
  float hist[4][KLAG];
  #pragma unroll
  for (int r = 0; r < 4; ++r){
    #pragma unroll
    for (int q = 0; q < KLAG; ++q) hist[r][q] = 0.f;
  }

  const u16* wbase = wp + (size_t)gh*(3*KKT*64*8);
  const int arow  = w*16 + lr;       // A-fragment row (batch index)
  const int browb = w*16 + lg*4;     // C-fragment base row (batch index)

  for (int t = 0; t < TT; ++t){
    // wait for all producers of step-t h data
    if (tid < GWG){
      while (__hip_atomic_load(flags + tid*16, __ATOMIC_RELAXED, __HIP_MEMORY_SCOPE_AGENT) < t){
        __builtin_amdgcn_s_sleep(1);
      }
      __builtin_amdgcn_fence(__ATOMIC_ACQUIRE, "agent");
    }
    __syncthreads();

    f32x4 acc0 = {0.f,0.f,0.f,0.f};
    f32x4 acc1 = {0.f,0.f,0.f,0.f};
    f32x4 acc2 = {0.f,0.f,0.f,0.f};
    const u16* hrow = hex + (size_t)(t & 1)*(BB*HH) + (size_t)arow*HH + lg*8;
    const u16* xrow = xb + ((size_t)t*BB + arow)*II + lg*8;
    #pragma unroll
    for (int kk = 0; kk < KKT; ++kk){
      short8 a = (kk < KKX)
        ? *(const short8*)(xrow + kk*32)
        : *(const short8*)(hrow + (kk-KKX)*32);
      const u16* wk = wbase + (size_t)kk*(64*8) + l*8;
      short8 b0 = *(const short8*)(wk);
      short8 b1 = *(const short8*)(wk + (size_t)1*KKT*64*8);
      short8 b2 = *(const short8*)(wk + (size_t)2*KKT*64*8);
      acc0 = __builtin_amdgcn_mfma_f32_16x16x32_bf16(a, b0, acc0, 0,0,0);
      acc1 = __builtin_amdgcn_mfma_f32_16x16x32_bf16(a, b1, acc1, 0,0,0);
      acc2 = __builtin_amdgcn_mfma_f32_16x16x32_bf16(a, b2, acc2, 0,0,0);
    }

    u16* hdst = hex  + (size_t)((t+1)&1)*(BB*HH);
    u16* hsq  = hseq + (size_t)t*(BB*HH);
    #pragma unroll
    for (int r = 0; r < 4; ++r){
      float ig = sigmoidf_(acc0[r] + bi);
      float og = sigmoidf_(acc1[r] + bo);
      float gg = tanhf_(acc2[r] + bc);
      float fs = 0.f;
      #pragma unroll
      for (int q = 0; q < KLAG; ++q) fs = __builtin_fmaf(v[q], hist[r][q], fs);
      float c = ig*gg - fs;
      #pragma unroll
      for (int q = KLAG-1; q > 0; --q) hist[r][q] = hist[r][q-1];
      hist[r][0] = c;
      float h = og * tanhf_(c);
      u16 hb = f2bf(h);
      int row = browb + r;
      hdst[(size_t)row*HH + ch] = hb;
      hsq [(size_t)row*HH + ch] = hb;
      if (t == TT-1) hlast[(size_t)row*HH + ch] = h;
    }

    __syncthreads();  // all h stores issued (vmcnt drained) before release
    if (tid == 0){
      __builtin_amdgcn_fence(__ATOMIC_RELEASE, "agent");
      __hip_atomic_store(flags + gh*16, t+1, __ATOMIC_RELAXED, __HIP_MEMORY_SCOPE_AGENT);
    }
  }

  // hc_last[k][b][h] = c_{480+k} = hist[31-k]
  #pragma unroll
  for (int r = 0; r < 4; ++r){
    int row = browb + r;
    #pragma unroll
    for (int q = 0; q < KLAG; ++q){
      hclast[(size_t)(KLAG-1-q)*(BB*HH) + (size_t)row*HH + ch] = hist[r][q];
    }
  }
}

// ---- deferred output GEMM: out[T*B,128] = hseq[T*B,512] @ W_out + b_out ----
__global__ __launch_bounds__(256) void k_out(
    const u16* __restrict__ hseq, const u16* __restrict__ wop,
    const float* __restrict__ b_out, float* __restrict__ out)
{
  const int tid = threadIdx.x, w = tid>>6, l = tid&63, lg = l>>4, lr = l&15;
  const size_t rbase = (size_t)blockIdx.x*64 + (size_t)w*16;
  f32x4 acc[8];
  #pragma unroll
  for (int n = 0; n < 8; ++n) acc[n] = (f32x4){0.f,0.f,0.f,0.f};
  const u16* arow_p = hseq + (rbase + lr)*HH + lg*8;
  #pragma unroll
  for (int kk = 0; kk < 16; ++kk){
    short8 a = *(const short8*)(arow_p + kk*32);
    #pragma unroll
    for (int n = 0; n < 8; ++n){
      short8 b = *(const short8*)(wop + ((size_t)(n*16 + kk)*64 + l)*8);
      acc[n] = __builtin_amdgcn_mfma_f32_16x16x32_bf16(a, b, acc[n], 0,0,0);
    }
  }
  #pragma unroll
  for (int n = 0; n < 8; ++n){
    int col = n*16 + lr;
    float bb = b_out[col];
    #pragma unroll
    for (int r = 0; r < 4; ++r)
      out[(rbase + lg*4 + r)*OO + col] = acc[n][r] + bb;
  }
}

extern "C" void kernel_launch(void* const* d_in, const int* in_sizes, int n_in,
                              void* d_out, int out_size, void* d_ws, size_t ws_size,
                              hipStream_t stream){
  const float* x    = (const float*)d_in[0];
  const float* Wi   = (const float*)d_in[1];
  const float* bi   = (const float*)d_in[2];
  const float* Wo   = (const float*)d_in[3];
  const float* bo   = (const float*)d_in[4];
  const float* Wc   = (const float*)d_in[5];
  const float* bc   = (const float*)d_in[6];
  const float* Wout = (const float*)d_in[7];
  const float* bout = (const float*)d_in[8];
  const float* dv   = (const float*)d_in[9];

  char* ws = (char*)d_ws;
  u16* xb    = (u16*)(ws);                 //  8,388,608 B  [T][B][128] bf16
  u16* wp    = (u16*)(ws + 8388608);       //  1,966,080 B  packed gate weights
  u16* wop   = (u16*)(ws + 10354688);      //    131,072 B  packed W_out
  u16* hseq  = (u16*)(ws + 10485760);      // 33,554,432 B  [T][B][H] bf16
  u16* hex   = (u16*)(ws + 44040192);      //    131,072 B  [2][B][H] bf16
  int* flags = (int*)(ws + 44171264);      //      2,048 B

  float* outp   = (float*)d_out;
  float* hlast  = outp + (size_t)TT*BB*OO;
  float* hclast = hlast + (size_t)BB*HH;

  hipLaunchKernelGGL(k_cast_x, dim3(4096), dim3(256), 0, stream, x, xb, TT*BB*II/4);
  hipLaunchKernelGGL(k_pack_w, dim3(3840), dim3(256), 0, stream, Wi, Wo, Wc, wp);
  hipLaunchKernelGGL(k_pack_wo, dim3(256), dim3(256), 0, stream, Wout, wop);
  hipLaunchKernelGGL(k_zero, dim3(128), dim3(256), 0, stream, (unsigned int*)hex, (BB*HH*2*2)/4, flags);
  hipLaunchKernelGGL(k_recur, dim3(GWG), dim3(256), 0, stream,
                     xb, wp, bi, bo, bc, dv, hex, hseq, hlast, hclast, flags);
  hipLaunchKernelGGL(k_out, dim3(512), dim3(256), 0, stream, hseq, wop, bout, outp);
}

// Round 2
// 3380.381 us; speedup vs baseline: 1.1281x; 1.1281x over previous
//
#include <hip/hip_runtime.h>
#include <hip/hip_bf16.h>

#define TT 512
#define BB 64
#define II 128
#define HH 512
#define OO 128
#define KLAG 32
#define GWG 32      // h-slice workgroups (16 channels each)
#define HC 16
#define KKX 4       // K-blocks (of 32) coming from x
#define KKT 20      // total K-blocks (640/32)

typedef __attribute__((ext_vector_type(8))) short short8;
typedef __attribute__((ext_vector_type(4))) int   i32x4;
typedef __attribute__((ext_vector_type(4))) float f32x4;
typedef unsigned short u16;

__device__ __forceinline__ float sigmoidf_(float x){ return 1.f/(1.f+__expf(-x)); }
__device__ __forceinline__ float tanhf_(float x){ float e = __expf(2.f*x); return 1.f - 2.f/(e+1.f); }
__device__ __forceinline__ u16 f2bf(float f){
  __hip_bfloat16 h = __float2bfloat16(f);
  u16 u; __builtin_memcpy(&u, &h, 2); return u;
}

// coherent (MALL-level) accesses: bypass L1/L2 via sc0 sc1
__device__ __forceinline__ short8 ld_sc_b128(const u16* p){
  i32x4 r;
  asm volatile("global_load_dwordx4 %0, %1, off sc0 sc1" : "=v"(r) : "v"(p));
  return __builtin_bit_cast(short8, r);
}
__device__ __forceinline__ void st_sc_b16(u16* p, unsigned int v){
  asm volatile("global_store_short %0, %1, off sc0 sc1" :: "v"(p), "v"(v) : "memory");
}

// ---- prep: cast inputs x to bf16 ([T][B][128]) ----
__global__ void k_cast_x(const float* __restrict__ x, u16* __restrict__ xb, int n4){
  int i = blockIdx.x*256 + threadIdx.x;
  if (i >= n4) return;
  float4 v = ((const float4*)x)[i];
  ushort4 o;
  o.x = f2bf(v.x); o.y = f2bf(v.y); o.z = f2bf(v.z); o.w = f2bf(v.w);
  ((ushort4*)xb)[i] = o;
}

// ---- prep: pack W_i/W_o/W_c into MFMA B-fragment layout ----
// flat idx = (((gh*3+gate)*KKT + kk)*64 + lane)*8 + j
__global__ void k_pack_w(const float* __restrict__ Wi, const float* __restrict__ Wo,
                         const float* __restrict__ Wc, u16* __restrict__ wp){
  int idx = blockIdx.x*256 + threadIdx.x;          // 983040 total
  int j    = idx & 7;
  int lane = (idx >> 3) & 63;
  int kk   = (idx >> 9) % KKT;
  int rest = (idx >> 9) / KKT;
  int gate = rest % 3;
  int gh   = rest / 3;
  int k    = kk*32 + ((lane>>4)<<3) + j;           // row of W (0..639)
  int col  = gh*HC + (lane & 15);                  // col of W (0..511)
  const float* W = (gate==0) ? Wi : ((gate==1) ? Wo : Wc);
  wp[idx] = f2bf(W[(size_t)k*HH + col]);
}

// ---- prep: pack W_out, flat idx = ((nt*16+kk)*64+lane)*8+j ----
__global__ void k_pack_wo(const float* __restrict__ Wout, u16* __restrict__ wp){
  int idx = blockIdx.x*256 + threadIdx.x;          // 65536 total
  int j    = idx & 7;
  int lane = (idx >> 3) & 63;
  int kk   = (idx >> 9) & 15;
  int nt   = idx >> 13;
  int k    = kk*32 + ((lane>>4)<<3) + j;           // 0..511
  int col  = nt*16 + (lane & 15);                  // 0..127
  wp[idx] = f2bf(Wout[(size_t)k*OO + col]);
}

// ---- prep: zero h slot 0 (h_{-1}=0) + flags ----
__global__ void k_zero(unsigned int* __restrict__ h0_u32, int n, int* __restrict__ flags){
  int i = blockIdx.x*256 + threadIdx.x;
  if (i < n) h0_u32[i] = 0;
  if (blockIdx.x == 0){
    for (int f = threadIdx.x; f < GWG*16; f += 256) flags[f] = 0;
  }
}

// ---- persistent recurrence kernel: 32 WGs x 256 threads ----
// hsq: [TT+1][B][H] bf16; slot 0 = zeros, slot t+1 = h_t (exchange AND output seq)
__global__ __launch_bounds__(256, 1) void k_recur(
    const u16* __restrict__ xb,
    const u16* __restrict__ wp,
    const float* __restrict__ bi_p, const float* __restrict__ bo_p,
    const float* __restrict__ bc_p, const float* __restrict__ dv,
    u16* __restrict__ hsq,
    float* __restrict__ hlast,         // [B][H] f32
    float* __restrict__ hclast,        // [K][B][H] f32
    int* __restrict__ flags)           // [32*16] padded (64B apart)
{
  const int gh  = blockIdx.x;
  const int tid = threadIdx.x;
  const int w = tid >> 6, l = tid & 63, lg = l >> 4, lr = l & 15;
  const int ch = gh*HC + lr;                     // global channel for this thread's outputs

  // fractional-differencing weights v_1..v_32 for this channel
  float d = 0.5f * sigmoidf_(dv[ch]);
  float v[KLAG];
  float vc = 1.f;
  #pragma unroll
  for (int j = 0; j < KLAG; ++j){ vc *= ((float)j - d)/((float)(j+1)); v[j] = vc; }
  const float bi = bi_p[ch], bo = bo_p[ch], bc = bc_p[ch];

  // c history in registers: hist[r][q] = c_{t-1-q} for batch row (browb+r)
  float hist[4][KLAG];
  #pragma unroll
  for (int r = 0; r < 4; ++r){
    #pragma unroll
    for (int q = 0; q < KLAG; ++q) hist[r][q] = 0.f;
  }

  const u16* wbase = wp + (size_t)gh*(3*KKT*64*8);
  const int arow  = w*16 + lr;       // A-fragment row (batch index)
  const int browb = w*16 + lg*4;     // C-fragment base row (batch index)

  for (int t = 0; t < TT; ++t){
    // ---- h-independent work first (off the sync critical path) ----
    // fractional-differencing dot product from register history
    float fs[4];
    #pragma unroll
    for (int r = 0; r < 4; ++r){
      float s = 0.f;
      #pragma unroll
      for (int q = 0; q < KLAG; ++q) s = __builtin_fmaf(v[q], hist[r][q], s);
      fs[r] = s;
    }
    // x-part MFMAs (weights + x are L2-resident: normal cached loads)
    f32x4 acc0 = {0.f,0.f,0.f,0.f};
    f32x4 acc1 = {0.f,0.f,0.f,0.f};
    f32x4 acc2 = {0.f,0.f,0.f,0.f};
    const u16* xrow = xb + ((size_t)t*BB + arow)*II + lg*8;
    #pragma unroll
    for (int kk = 0; kk < KKX; ++kk){
      short8 a = *(const short8*)(xrow + kk*32);
      const u16* wk = wbase + (size_t)kk*(64*8) + l*8;
      short8 b0 = *(const short8*)(wk);
      short8 b1 = *(const short8*)(wk + (size_t)1*KKT*64*8);
      short8 b2 = *(const short8*)(wk + (size_t)2*KKT*64*8);
      acc0 = __builtin_amdgcn_mfma_f32_16x16x32_bf16(a, b0, acc0, 0,0,0);
      acc1 = __builtin_amdgcn_mfma_f32_16x16x32_bf16(a, b1, acc1, 0,0,0);
      acc2 = __builtin_amdgcn_mfma_f32_16x16x32_bf16(a, b2, acc2, 0,0,0);
    }

    // ---- wait for all producers of h_{t-1} (slot t) ----
    if (tid < GWG){
      while (__hip_atomic_load(flags + tid*16, __ATOMIC_RELAXED, __HIP_MEMORY_SCOPE_AGENT) < t){ }
    }
    __syncthreads();

    // ---- coherent h loads (bypass L1/L2 -> MALL), then h-part MFMAs ----
    const u16* hrow = hsq + (size_t)t*(BB*HH) + (size_t)arow*HH + lg*8;
    short8 ha[16];
    #pragma unroll
    for (int kk = 0; kk < 16; ++kk) ha[kk] = ld_sc_b128(hrow + kk*32);
    asm volatile("s_waitcnt vmcnt(0)" ::: "memory");
    __builtin_amdgcn_sched_barrier(0);
    #pragma unroll
    for (int kk = 0; kk < 16; ++kk){
      const u16* wk = wbase + (size_t)(kk+KKX)*(64*8) + l*8;
      short8 b0 = *(const short8*)(wk);
      short8 b1 = *(const short8*)(wk + (size_t)1*KKT*64*8);
      short8 b2 = *(const short8*)(wk + (size_t)2*KKT*64*8);
      acc0 = __builtin_amdgcn_mfma_f32_16x16x32_bf16(ha[kk], b0, acc0, 0,0,0);
      acc1 = __builtin_amdgcn_mfma_f32_16x16x32_bf16(ha[kk], b1, acc1, 0,0,0);
      acc2 = __builtin_amdgcn_mfma_f32_16x16x32_bf16(ha[kk], b2, acc2, 0,0,0);
    }

    // ---- epilogue: gates, c, h; coherent store of h slice ----
    u16* hdst = hsq + (size_t)(t+1)*(BB*HH);
    #pragma unroll
    for (int r = 0; r < 4; ++r){
      float ig = sigmoidf_(acc0[r] + bi);
      float og = sigmoidf_(acc1[r] + bo);
      float gg = tanhf_(acc2[r] + bc);
      float c = ig*gg - fs[r];
      #pragma unroll
      for (int q = KLAG-1; q > 0; --q) hist[r][q] = hist[r][q-1];
      hist[r][0] = c;
      float h = og * tanhf_(c);
      int row = browb + r;
      st_sc_b16(hdst + (size_t)row*HH + ch, (unsigned int)f2bf(h));
      if (t == TT-1) hlast[(size_t)row*HH + ch] = h;
    }
    asm volatile("s_waitcnt vmcnt(0)" ::: "memory");   // h writes ack'd at MALL
    __syncthreads();                                    // all 4 waves done
    if (tid == 0){
      // release: orders (already-drained) writes before flag; wbl2 is cheap
      // (loop stores are sc write-through -> no dirty L2; clean weights stay)
      __hip_atomic_store(flags + gh*16, t+1, __ATOMIC_RELEASE, __HIP_MEMORY_SCOPE_AGENT);
    }
  }

  // hc_last[k][b][h] = c_{480+k} = hist[31-k]
  #pragma unroll
  for (int r = 0; r < 4; ++r){
    int row = browb + r;
    #pragma unroll
    for (int q = 0; q < KLAG; ++q){
      hclast[(size_t)(KLAG-1-q)*(BB*HH) + (size_t)row*HH + ch] = hist[r][q];
    }
  }
}

// ---- deferred output GEMM: out[T*B,128] = hseq[T*B,512] @ W_out + b_out ----
__global__ __launch_bounds__(256) void k_out(
    const u16* __restrict__ hseq, const u16* __restrict__ wop,
    const float* __restrict__ b_out, float* __restrict__ out)
{
  const int tid = threadIdx.x, w = tid>>6, l = tid&63, lg = l>>4, lr = l&15;
  const size_t rbase = (size_t)blockIdx.x*64 + (size_t)w*16;
  f32x4 acc[8];
  #pragma unroll
  for (int n = 0; n < 8; ++n) acc[n] = (f32x4){0.f,0.f,0.f,0.f};
  const u16* arow_p = hseq + (rbase + lr)*HH + lg*8;
  #pragma unroll
  for (int kk = 0; kk < 16; ++kk){
    short8 a = *(const short8*)(arow_p + kk*32);
    #pragma unroll
    for (int n = 0; n < 8; ++n){
      short8 b = *(const short8*)(wop + ((size_t)(n*16 + kk)*64 + l)*8);
      acc[n] = __builtin_amdgcn_mfma_f32_16x16x32_bf16(a, b, acc[n], 0,0,0);
    }
  }
  #pragma unroll
  for (int n = 0; n < 8; ++n){
    int col = n*16 + lr;
    float bb = b_out[col];
    #pragma unroll
    for (int r = 0; r < 4; ++r)
      out[(rbase + lg*4 + r)*OO + col] = acc[n][r] + bb;
  }
}

extern "C" void kernel_launch(void* const* d_in, const int* in_sizes, int n_in,
                              void* d_out, int out_size, void* d_ws, size_t ws_size,
                              hipStream_t stream){
  const float* x    = (const float*)d_in[0];
  const float* Wi   = (const float*)d_in[1];
  const float* bi   = (const float*)d_in[2];
  const float* Wo   = (const float*)d_in[3];
  const float* bo   = (const float*)d_in[4];
  const float* Wc   = (const float*)d_in[5];
  const float* bc   = (const float*)d_in[6];
  const float* Wout = (const float*)d_in[7];
  const float* bout = (const float*)d_in[8];
  const float* dv   = (const float*)d_in[9];

  char* ws = (char*)d_ws;
  u16* xb    = (u16*)(ws);                 //  8,388,608 B  [T][B][128] bf16
  u16* wp    = (u16*)(ws + 8388608);       //  1,966,080 B  packed gate weights
  u16* wop   = (u16*)(ws + 10354688);      //    131,072 B  packed W_out
  u16* hsq   = (u16*)(ws + 10485760);      // 33,619,968 B  [TT+1][B][H] bf16 (slot0=0)
  int* flags = (int*)(ws + 44105728);      //      2,048 B

  float* outp   = (float*)d_out;
  float* hlast  = outp + (size_t)TT*BB*OO;
  float* hclast = hlast + (size_t)BB*HH;

  hipLaunchKernelGGL(k_cast_x, dim3(4096), dim3(256), 0, stream, x, xb, TT*BB*II/4);
  hipLaunchKernelGGL(k_pack_w, dim3(3840), dim3(256), 0, stream, Wi, Wo, Wc, wp);
  hipLaunchKernelGGL(k_pack_wo, dim3(256), dim3(256), 0, stream, Wout, wop);
  hipLaunchKernelGGL(k_zero, dim3(64), dim3(256), 0, stream, (unsigned int*)hsq, (BB*HH*2)/4, flags);
  hipLaunchKernelGGL(k_recur, dim3(GWG), dim3(256), 0, stream,
                     xb, wp, bi, bo, bc, dv, hsq, hlast, hclast, flags);
  hipLaunchKernelGGL(k_out, dim3(512), dim3(256), 0, stream, hsq + (size_t)BB*HH, wop, bout, outp);
}

// Round 4
// 2887.982 us; speedup vs baseline: 1.3205x; 1.1705x over previous
//
#include <hip/hip_runtime.h>
#include <hip/hip_bf16.h>

#define TT 512
#define BB 64
#define II 128
#define HH 512
#define OO 128
#define KLAG 32
#define GWG 32      // h-slice workgroups per replica (16 channels each)
#define HC 16
#define KKX 4       // K-blocks (of 32) coming from x
#define KKT 20      // total K-blocks (640/32)
#define NXCD 8

typedef __attribute__((ext_vector_type(8))) short short8;
typedef __attribute__((ext_vector_type(4))) int   i32x4;
typedef __attribute__((ext_vector_type(4))) float f32x4;
typedef unsigned short u16;

__device__ __forceinline__ float sigmoidf_(float x){ return 1.f/(1.f+__expf(-x)); }
__device__ __forceinline__ float tanhf_(float x){ float e = __expf(2.f*x); return 1.f - 2.f/(e+1.f); }
__device__ __forceinline__ u16 f2bf(float f){
  __hip_bfloat16 h = __float2bfloat16(f);
  u16 u; __builtin_memcpy(&u, &h, 2); return u;
}

// ---- prep: cast inputs x to bf16 ([T][B][128]) ----
__global__ void k_cast_x(const float* __restrict__ x, u16* __restrict__ xb, int n4){
  int i = blockIdx.x*256 + threadIdx.x;
  if (i >= n4) return;
  float4 v = ((const float4*)x)[i];
  ushort4 o;
  o.x = f2bf(v.x); o.y = f2bf(v.y); o.z = f2bf(v.z); o.w = f2bf(v.w);
  ((ushort4*)xb)[i] = o;
}

// ---- prep: pack W_i/W_o/W_c into MFMA B-fragment layout ----
// flat idx = (((gh*3+gate)*KKT + kk)*64 + lane)*8 + j
__global__ void k_pack_w(const float* __restrict__ Wi, const float* __restrict__ Wo,
                         const float* __restrict__ Wc, u16* __restrict__ wp){
  int idx = blockIdx.x*256 + threadIdx.x;          // 983040 total
  int j    = idx & 7;
  int lane = (idx >> 3) & 63;
  int kk   = (idx >> 9) % KKT;
  int rest = (idx >> 9) / KKT;
  int gate = rest % 3;
  int gh   = rest / 3;
  int k    = kk*32 + ((lane>>4)<<3) + j;           // row of W (0..639)
  int col  = gh*HC + (lane & 15);                  // col of W (0..511)
  const float* W = (gate==0) ? Wi : ((gate==1) ? Wo : Wc);
  wp[idx] = f2bf(W[(size_t)k*HH + col]);
}

// ---- prep: pack W_out, flat idx = ((nt*16+kk)*64+lane)*8+j ----
__global__ void k_pack_wo(const float* __restrict__ Wout, u16* __restrict__ wp){
  int idx = blockIdx.x*256 + threadIdx.x;          // 65536 total
  int j    = idx & 7;
  int lane = (idx >> 3) & 63;
  int kk   = (idx >> 9) & 15;
  int nt   = idx >> 13;
  int k    = kk*32 + ((lane>>4)<<3) + j;           // 0..511
  int col  = nt*16 + (lane & 15);                  // 0..127
  wp[idx] = f2bf(Wout[(size_t)k*OO + col]);
}

// ---- prep: zero h slot 0 + flags/rosters/done ----
__global__ void k_zero(unsigned int* __restrict__ h0, unsigned int* __restrict__ misc){
  int i = blockIdx.x*256 + threadIdx.x;
  if (i < 16384) h0[i] = 0;
  else if (i < 16384 + 4240) misc[i - 16384] = 0;
}

// ---- persistent recurrence kernel, per-XCD replicated ----
// hsq: [TT+1][B][H] bf16; slot 0 = zeros, slot t+1 = h_t
__global__ __launch_bounds__(256, 1) void k_recur(
    const u16* __restrict__ xb,
    const u16* __restrict__ wp,
    const float* __restrict__ bi_p, const float* __restrict__ bo_p,
    const float* __restrict__ bc_p, const float* __restrict__ dv,
    u16* __restrict__ hsq,
    float* __restrict__ hlast,         // [B][H] f32
    float* __restrict__ hclast,        // [K][B][H] f32
    int* flags,                        // [NXCD][32] ints, padded *16
    int* rost,                         // [NXCD] ints, padded *16
    int* done)                         // 1 int
{
  __shared__ u16 wlds[3*16*64*8];      // h-part weights (kk=4..19), 49152 B
  __shared__ int sslot, sxcd, sbail;
  const int tid = threadIdx.x;
  if (tid == 0){
    unsigned int xcd;
    asm volatile("s_getreg_b32 %0, hwreg(HW_REG_XCC_ID)" : "=s"(xcd));
    sxcd  = (int)(xcd & 7);
    sslot = __hip_atomic_fetch_add(rost + (xcd & 7)*16, 1,
                                   __ATOMIC_RELAXED, __HIP_MEMORY_SCOPE_AGENT);
    sbail = 0;
  }
  __syncthreads();
  const int gh = sslot, xcd = sxcd;
  if (gh >= GWG) return;

  // one-time: drop stale clean L2 lines (belt & braces; dispatch acquire
  // should already have done this)
  __builtin_amdgcn_fence(__ATOMIC_ACQUIRE, "agent");

  const u16* wbase = wp + (size_t)gh*(3*KKT*64*8);
  // stage h-part weights into LDS: [g][kkh][lane][8], kkh = kk-4
  for (int i = tid*8; i < 3*16*64*8; i += 256*8){
    int e = i & 511;
    int blk = i >> 9;                  // 0..47
    int g = blk >> 4, kkh = blk & 15;
    *(short8*)&wlds[i] = *(const short8*)(wbase + (size_t)(g*KKT + KKX + kkh)*512 + e);
  }
  const int w = tid >> 6, l = tid & 63, lg = l >> 4, lr = l & 15;
  // x-part weight fragments in registers
  short8 bx[KKX][3];
  #pragma unroll
  for (int kk = 0; kk < KKX; ++kk){
    #pragma unroll
    for (int g = 0; g < 3; ++g)
      bx[kk][g] = *(const short8*)(wbase + (size_t)(g*KKT + kk)*512 + l*8);
  }
  __syncthreads();

  const int ch = gh*HC + lr;
  float d = 0.5f * sigmoidf_(dv[ch]);
  float v[KLAG];
  float vc = 1.f;
  #pragma unroll
  for (int j = 0; j < KLAG; ++j){ vc *= ((float)j - d)/((float)(j+1)); v[j] = vc; }
  const float bi = bi_p[ch], bo = bo_p[ch], bc = bc_p[ch];

  float hist[4][KLAG];
  #pragma unroll
  for (int r = 0; r < 4; ++r){
    #pragma unroll
    for (int q = 0; q < KLAG; ++q) hist[r][q] = 0.f;
  }

  const int arow  = w*16 + lr;
  const int browb = w*16 + lg*4;
  int* fme = flags + (xcd*GWG + gh)*16;
  bool bailed = false;

  for (int t = 0; t < TT; ++t){
    u16* hdst = hsq + (size_t)(t+1)*(BB*HH);

    // ---- hoisted, h-independent ----
    float fs[4];
    #pragma unroll
    for (int r = 0; r < 4; ++r){
      float s = 0.f;
      #pragma unroll
      for (int q = 0; q < KLAG; ++q) s = __builtin_fmaf(v[q], hist[r][q], s);
      fs[r] = s;
    }
    f32x4 acc0 = {0.f,0.f,0.f,0.f};
    f32x4 acc1 = {0.f,0.f,0.f,0.f};
    f32x4 acc2 = {0.f,0.f,0.f,0.f};
    const u16* xrow = xb + ((size_t)t*BB + arow)*II + lg*8;
    #pragma unroll
    for (int kk = 0; kk < KKX; ++kk){
      short8 a = *(const short8*)(xrow + kk*32);
      acc0 = __builtin_amdgcn_mfma_f32_16x16x32_bf16(a, bx[kk][0], acc0, 0,0,0);
      acc1 = __builtin_amdgcn_mfma_f32_16x16x32_bf16(a, bx[kk][1], acc1, 0,0,0);
      acc2 = __builtin_amdgcn_mfma_f32_16x16x32_bf16(a, bx[kk][2], acc2, 0,0,0);
    }

    // ---- wait for local producers of h_{t-1} (slot t), local-L2 polls ----
    if (tid < GWG){
      const int* fp = flags + (xcd*GWG + tid)*16;
      int it = 0;
      while (true){
        int fv;
        asm volatile("global_load_dword %0, %1, off sc0\ns_waitcnt vmcnt(0)"
                     : "=v"(fv) : "v"(fp));
        if (fv >= t) break;
        if (((++it) & 63) == 0){
          int dn;
          asm volatile("global_load_dword %0, %1, off sc0 sc1\ns_waitcnt vmcnt(0)"
                       : "=v"(dn) : "v"(done));
          if (dn){ sbail = 1; break; }
        }
      }
    }
    __syncthreads();
    if (sbail){ bailed = true; break; }

    // ---- h loads from local L2, then h-part MFMAs (B from LDS) ----
    const u16* hrow = hsq + (size_t)t*(BB*HH) + (size_t)arow*HH + lg*8;
    short8 ha[16];
    #pragma unroll
    for (int kk = 0; kk < 16; ++kk){
      i32x4 r;
      asm volatile("global_load_dwordx4 %0, %1, off sc0" : "=v"(r) : "v"(hrow + kk*32));
      ha[kk] = __builtin_bit_cast(short8, r);
    }
    asm volatile("s_waitcnt vmcnt(0)" ::: "memory");
    __builtin_amdgcn_sched_barrier(0);
    #pragma unroll
    for (int kk = 0; kk < 16; ++kk){
      short8 b0 = *(const short8*)&wlds[(size_t)((0*16 + kk)*64 + l)*8];
      short8 b1 = *(const short8*)&wlds[(size_t)((1*16 + kk)*64 + l)*8];
      short8 b2 = *(const short8*)&wlds[(size_t)((2*16 + kk)*64 + l)*8];
      acc0 = __builtin_amdgcn_mfma_f32_16x16x32_bf16(ha[kk], b0, acc0, 0,0,0);
      acc1 = __builtin_amdgcn_mfma_f32_16x16x32_bf16(ha[kk], b1, acc1, 0,0,0);
      acc2 = __builtin_amdgcn_mfma_f32_16x16x32_bf16(ha[kk], b2, acc2, 0,0,0);
    }

    // ---- epilogue: gates, c, h; store h slice to local L2 ----
    #pragma unroll
    for (int r = 0; r < 4; ++r){
      float ig = sigmoidf_(acc0[r] + bi);
      float og = sigmoidf_(acc1[r] + bo);
      float gg = tanhf_(acc2[r] + bc);
      float c = ig*gg - fs[r];
      #pragma unroll
      for (int q = KLAG-1; q > 0; --q) hist[r][q] = hist[r][q-1];
      hist[r][0] = c;
      float h = og * tanhf_(c);
      int row = browb + r;
      unsigned int hb = (unsigned int)f2bf(h);
      u16* sp = hdst + (size_t)row*HH + ch;
      asm volatile("global_store_short %0, %1, off sc0" :: "v"(sp), "v"(hb) : "memory");
      if (t == TT-1) hlast[(size_t)row*HH + ch] = h;
    }
    asm volatile("s_waitcnt vmcnt(0)" ::: "memory");   // h in local L2
    __syncthreads();
    if (tid == 0){
      int val = t+1;
      asm volatile("global_store_dword %0, %1, off sc0" :: "v"(fme), "v"(val) : "memory");
    }
  }

  if (!bailed){
    #pragma unroll
    for (int r = 0; r < 4; ++r){
      int row = browb + r;
      #pragma unroll
      for (int q = 0; q < KLAG; ++q)
        hclast[(size_t)(KLAG-1-q)*(BB*HH) + (size_t)row*HH + ch] = hist[r][q];
    }
    if (tid == 0){
      int one = 1;
      asm volatile("global_store_dword %0, %1, off sc0 sc1" :: "v"(done), "v"(one) : "memory");
    }
  }
}

// ---- deferred output GEMM: out[T*B,128] = hseq[T*B,512] @ W_out + b_out ----
__global__ __launch_bounds__(256) void k_out(
    const u16* __restrict__ hseq, const u16* __restrict__ wop,
    const float* __restrict__ b_out, float* __restrict__ out)
{
  const int tid = threadIdx.x, w = tid>>6, l = tid&63, lg = l>>4, lr = l&15;
  const size_t rbase = (size_t)blockIdx.x*64 + (size_t)w*16;
  f32x4 acc[8];
  #pragma unroll
  for (int n = 0; n < 8; ++n) acc[n] = (f32x4){0.f,0.f,0.f,0.f};
  const u16* arow_p = hseq + (rbase + lr)*HH + lg*8;
  #pragma unroll
  for (int kk = 0; kk < 16; ++kk){
    short8 a = *(const short8*)(arow_p + kk*32);
    #pragma unroll
    for (int n = 0; n < 8; ++n){
      short8 b = *(const short8*)(wop + ((size_t)(n*16 + kk)*64 + l)*8);
      acc[n] = __builtin_amdgcn_mfma_f32_16x16x32_bf16(a, b, acc[n], 0,0,0);
    }
  }
  #pragma unroll
  for (int n = 0; n < 8; ++n){
    int col = n*16 + lr;
    float bb = b_out[col];
    #pragma unroll
    for (int r = 0; r < 4; ++r)
      out[(rbase + lg*4 + r)*OO + col] = acc[n][r] + bb;
  }
}

extern "C" void kernel_launch(void* const* d_in, const int* in_sizes, int n_in,
                              void* d_out, int out_size, void* d_ws, size_t ws_size,
                              hipStream_t stream){
  const float* x    = (const float*)d_in[0];
  const float* Wi   = (const float*)d_in[1];
  const float* bi   = (const float*)d_in[2];
  const float* Wo   = (const float*)d_in[3];
  const float* bo   = (const float*)d_in[4];
  const float* Wc   = (const float*)d_in[5];
  const float* bc   = (const float*)d_in[6];
  const float* Wout = (const float*)d_in[7];
  const float* bout = (const float*)d_in[8];
  const float* dv   = (const float*)d_in[9];

  char* ws = (char*)d_ws;
  u16* xb    = (u16*)(ws);                 //  8,388,608 B
  u16* wp    = (u16*)(ws + 8388608);       //  1,966,080 B packed gate weights
  u16* wop   = (u16*)(ws + 10354688);      //    131,072 B packed W_out
  u16* hsq   = (u16*)(ws + 10485760);      // 33,619,968 B [TT+1][B][H] bf16
  int* flags = (int*)(ws + 44105728);      //     16,384 B [8][32]*16
  int* rost  = (int*)(ws + 44122112);      //        512 B [8]*16
  int* done  = (int*)(ws + 44122624);      //         64 B

  float* outp   = (float*)d_out;
  float* hlast  = outp + (size_t)TT*BB*OO;
  float* hclast = hlast + (size_t)BB*HH;

  hipLaunchKernelGGL(k_cast_x, dim3(4096), dim3(256), 0, stream, x, xb, TT*BB*II/4);
  hipLaunchKernelGGL(k_pack_w, dim3(3840), dim3(256), 0, stream, Wi, Wo, Wc, wp);
  hipLaunchKernelGGL(k_pack_wo, dim3(256), dim3(256), 0, stream, Wout, wop);
  hipLaunchKernelGGL(k_zero, dim3(81), dim3(256), 0, stream,
                     (unsigned int*)hsq, (unsigned int*)flags);
  hipLaunchKernelGGL(k_recur, dim3(256), dim3(256), 0, stream,
                     xb, wp, bi, bo, bc, dv, hsq, hlast, hclast, flags, rost, done);
  hipLaunchKernelGGL(k_out, dim3(512), dim3(256), 0, stream, hsq + (size_t)BB*HH, wop, bout, outp);
}